// Round 3
// baseline (489.432 us; speedup 1.0000x reference)
//
#include <hip/hip_runtime.h>

// LSTM B=256, T=1024, I=64, H=128. One block/batch row (256 blocks = 256 CUs).
// R11 = R10 with the h-GEMM switched f16 -> int8 (mfma_i32_16x16x64_i8, K=64):
//  - per-step pipe time 128 MFMA (~620cyc/CU) -> 64 i8-MFMA (~330cyc/CU).
//    R10's null result showed the step is issue-time + fixed-latency bound;
//    only a larger-K MFMA cuts the issue term.
//  - h quantized to i8 with fixed scale 127 (|h|<1 strictly, round-to-nearest)
//    and stored in LDS as bytes: 2x ds_read_b128 per step instead of 4.
//  - W_hh quantized per output row (= per lane column) with max-abs scale;
//    each lane dequantizes its own column: gate = f32(q)*dqh[g] + xw[g][R].
//    exp2 gate constants folded into dqh and the f16 x-path (unchanged).
//  - c, activations, x-projection remain f32/f16 exactly as R10.
// i8 A/B packing uses the same symmetric per-lane k-chunk layout as the
// (verified) f16 path; correctness follows from dot-product permutation
// invariance when A and B share the k-mapping function.

typedef _Float16 half8  __attribute__((ext_vector_type(8)));
typedef _Float16 half2t __attribute__((ext_vector_type(2)));
typedef float  floatx4  __attribute__((ext_vector_type(4)));
typedef int    intx4   __attribute__((ext_vector_type(4)));

constexpr int Tt = 1024;
constexpr int Ii = 64;
constexpr int Hh = 128;
constexpr int CH = 16;          // timesteps per x chunk-GEMM
constexpr int NCH = Tt / CH;    // 64 chunks

__device__ __forceinline__ float fast_rcp(float x) { return __builtin_amdgcn_rcpf(x); }
__device__ __forceinline__ float exp2_(float x)    { return __builtin_amdgcn_exp2f(x); }
__device__ __forceinline__ half2t pk16(float a, float b) {
    return __builtin_bit_cast(half2t, __builtin_amdgcn_cvt_pkrtz(a, b));
}
#define MFMA16(A, B, C) __builtin_amdgcn_mfma_f32_16x16x32_f16((A), (B), (C), 0, 0, 0)
#define MFMAI8(A, B, C) __builtin_amdgcn_mfma_i32_16x16x64_i8((A), (B), (C), 0, 0, 0)
union H8U { half8 v; half2t p[4]; };
union I8U { intx4 v; signed char c[16]; };

__device__ __forceinline__ half8 cvt8(float4 a, float4 b) {
    H8U u;
    u.p[0] = pk16(a.x, a.y); u.p[1] = pk16(a.z, a.w);
    u.p[2] = pk16(b.x, b.y); u.p[3] = pk16(b.z, b.w);
    return u.v;
}
__device__ __forceinline__ floatx4 splat4(float a) { floatx4 r = {a, a, a, a}; return r; }

__global__ __launch_bounds__(512, 1) void lstm_mfma7(
    const float* __restrict__ data,   // [B, T, I]
    const float* __restrict__ W_ih,   // [4H, I]
    const float* __restrict__ W_hh,   // [4H, H]
    const float* __restrict__ b_ih,   // [4H]
    const float* __restrict__ b_hh,   // [4H]
    float* __restrict__ out)          // [B, T, H] f32
{
    const int b   = blockIdx.x;
    const int t   = threadIdx.x;
    const int w   = t >> 6;    // wave 0..7
    const int l   = t & 63;    // lane
    const int col = l & 15;    // N-col == hidden unit offset within wave's 16
    const int kg  = l >> 4;    // k-group / C-row group

    // ---- weights static in VGPRs ----
    // gates 0(i),1(f),3(o): sigma(x)=rcp(1+exp2(-log2e*x))
    // gate 2(g):            tanh(x) via e=exp2(-2log2e*x), (1-e)*rcp(1+e)
    intx4 bqh[4][2];   // Whh int8: 4 gates x 2 K-slices (K=128 as 2x64)
    float dqh[4];      // per-gate-row dequant scale (sc folded)
    half8 bfx[4][2];   // Wih f16 (sc folded): 4 gates x 2 K-slices (K=64)
    float bs[4];       // scaled bias (x chunk-GEMM C-init)
#pragma unroll
    for (int g = 0; g < 4; ++g) {
        const float sc = (g == 2) ? -2.8853900817779268f : -1.4426950408889634f;
        const int row = 128 * g + 16 * w + col;
        bs[g] = sc * (b_ih[row] + b_hh[row]);
        const float* wh = W_hh + (size_t)row * Hh;
        const float* wi = W_ih + (size_t)row * Ii;
        // pass 1: row max-abs
        float mw = 1e-20f;
#pragma unroll
        for (int k = 0; k < Hh; k += 4) {
            const float4 f = *(const float4*)(wh + k);
            mw = fmaxf(mw, fmaxf(fmaxf(fabsf(f.x), fabsf(f.y)),
                                 fmaxf(fabsf(f.z), fabsf(f.w))));
        }
        const float qs = 127.f / mw;
        dqh[g] = sc * mw * (1.f / (127.f * 127.f));
        // pass 2: quantize this lane's 2 x 16-byte B fragments
#pragma unroll
        for (int s = 0; s < 2; ++s) {
            const float* src = wh + 64 * s + 16 * kg;
            I8U u;
#pragma unroll
            for (int j = 0; j < 16; ++j)
                u.c[j] = (signed char)(int)rintf(src[j] * qs);
            bqh[g][s] = u.v;
        }
        // x-projection weights stay f16 with sc folded
#pragma unroll
        for (int s = 0; s < 2; ++s) {
            const float* src = wi + 32 * s + 8 * kg;
            const float4 f0 = ((const float4*)src)[0];
            const float4 f1 = ((const float4*)src)[1];
            H8U u;
            u.p[0] = pk16(sc * f0.x, sc * f0.y); u.p[1] = pk16(sc * f0.z, sc * f0.w);
            u.p[2] = pk16(sc * f1.x, sc * f1.y); u.p[3] = pk16(sc * f1.z, sc * f1.w);
            bfx[g][s] = u.v;
        }
    }

    __shared__ __align__(16) signed char hbq[2][Hh];  // h i8 double buffer

    const float* xp  = data + (size_t)b * Tt * Ii;
    float*       opr = out  + (size_t)b * Tt * Hh + 16 * w + col;

    if (t < Hh) hbq[0][t] = 0;        // h0 = 0

    // x chunk staging: lane reads x[t0 + (l&15)][32*s2 + 8*kg + j], j=0..7
    const float* xbase = xp + (size_t)(l & 15) * Ii + 8 * kg;
    float4 xf0 = *(const float4*)(xbase);
    float4 xf1 = *(const float4*)(xbase + 4);
    float4 xf2 = *(const float4*)(xbase + 32);
    float4 xf3 = *(const float4*)(xbase + 36);

    // ---- prologue: chunk-0 xw, chunk-1 x loads in flight under it ----
    half8 ax0 = cvt8(xf0, xf1);
    half8 ax1 = cvt8(xf2, xf3);
    xf0 = *(const float4*)(xbase + CH * Ii);
    xf1 = *(const float4*)(xbase + CH * Ii + 4);
    xf2 = *(const float4*)(xbase + CH * Ii + 32);
    xf3 = *(const float4*)(xbase + CH * Ii + 36);
    floatx4 xw0 = MFMA16(ax0, bfx[0][0], splat4(bs[0]));
    floatx4 xw1 = MFMA16(ax0, bfx[1][0], splat4(bs[1]));
    floatx4 xw2 = MFMA16(ax0, bfx[2][0], splat4(bs[2]));
    floatx4 xw3 = MFMA16(ax0, bfx[3][0], splat4(bs[3]));
    xw0 = MFMA16(ax1, bfx[0][1], xw0);
    xw1 = MFMA16(ax1, bfx[1][1], xw1);
    xw2 = MFMA16(ax1, bfx[2][1], xw2);
    xw3 = MFMA16(ax1, bfx[3][1], xw3);

    half8 nax0, nax1;                 // next chunk's A fragments
    floatx4 nxw0, nxw1, nxw2, nxw3;   // next chunk's xW+bias accumulators

    float c = 0.0f;
    __syncthreads();   // h0 visible (one full drain, outside the loop)

#pragma unroll 1
    for (int n = 0; n < NCH; ++n) {
        const float* xb2 = xbase + (size_t)((n + 2 < NCH) ? n + 2 : NCH - 1) * CH * Ii;

        // step s = 16n + 4P + R; h buffer parity = R&1 (16n+4P even).
        // f,g,i 2-deep i8 chains first; o trails so the exposed tail is just
        // sigma(o)*tc + quant/pack/write.
#define STEP(P, R, CUR, XTRA)                                                 \
        {                                                                     \
            const signed char* hbase = &hbq[CUR][16 * kg];                    \
            const intx4 ah0 = *(const intx4*)(hbase);                         \
            const intx4 ah1 = *(const intx4*)(hbase + 64);                    \
            XTRA;                                                             \
            __builtin_amdgcn_s_setprio(1);                                    \
            const intx4 z4 = {0, 0, 0, 0};                                    \
            intx4 qf = MFMAI8(ah0, bqh[1][0], z4);   /* f */                  \
            intx4 qg = MFMAI8(ah0, bqh[2][0], z4);   /* g */                  \
            intx4 qi = MFMAI8(ah0, bqh[0][0], z4);   /* i */                  \
            qf = MFMAI8(ah1, bqh[1][1], qf);                                  \
            qg = MFMAI8(ah1, bqh[2][1], qg);                                  \
            qi = MFMAI8(ah1, bqh[0][1], qi);                                  \
            intx4 qo = MFMAI8(ah0, bqh[3][0], z4);   /* o */                  \
            const float fg = fast_rcp(1.0f + exp2_(fmaf((float)qf[R], dqh[1], xw1[R]))); \
            const float eg = exp2_(fmaf((float)qg[R], dqh[2], xw2[R]));       \
            qo = MFMAI8(ah1, bqh[3][1], qo);                                  \
            const float fc = fg * c;                                          \
            const float gv = (1.0f - eg) * fast_rcp(1.0f + eg);               \
            const float ig = fast_rcp(1.0f + exp2_(fmaf((float)qi[R], dqh[0], xw0[R]))); \
            __builtin_amdgcn_s_setprio(0);                                    \
            c = fmaf(ig, gv, fc);                                             \
            const float ec = exp2_(-2.8853900817779268f * c);                 \
            const float tc = (1.0f - ec) * fast_rcp(1.0f + ec);               \
            const float og = fast_rcp(1.0f + exp2_(fmaf((float)qo[R], dqh[3], xw3[R]))); \
            const float h  = og * tc;                                         \
            if (kg == (P)) {                                                  \
                hbq[(CUR) ^ 1][16 * w + col] =                                \
                    (signed char)(int)rintf(h * 127.f);                       \
                *opr = h;                                                     \
            }                                                                 \
            opr += Hh;                                                        \
            asm volatile("s_waitcnt lgkmcnt(0)\n\ts_barrier" ::: "memory");   \
        }

        // phase P handles steps 4P..4P+3; c lineage hops lane-groups:
        // rotate c from group P-1 (or prev chunk's group 3) into group P.
        // Rotation rides the R==0 XTRA slot (after the ds_read issues).
#define PHASE(P, X0, X1, X2, X3)                                              \
        STEP(P, 0, 0, X0) STEP(P, 1, 1, X1) STEP(P, 2, 0, X2) STEP(P, 3, 1, X3)

        PHASE(0,
              (c = __shfl(c, (l + 48) & 63), nax0 = cvt8(xf0, xf1)),
              nax1 = cvt8(xf2, xf3),
              nxw0 = MFMA16(nax0, bfx[0][0], splat4(bs[0])),
              nxw1 = MFMA16(nax0, bfx[1][0], splat4(bs[1])))
        PHASE(1,
              (c = __shfl(c, (l + 48) & 63), nxw2 = MFMA16(nax0, bfx[2][0], splat4(bs[2]))),
              nxw3 = MFMA16(nax0, bfx[3][0], splat4(bs[3])),
              nxw0 = MFMA16(nax1, bfx[0][1], nxw0),
              nxw1 = MFMA16(nax1, bfx[1][1], nxw1))
        PHASE(2,
              (c = __shfl(c, (l + 48) & 63), nxw2 = MFMA16(nax1, bfx[2][1], nxw2)),
              nxw3 = MFMA16(nax1, bfx[3][1], nxw3),
              xf0 = *(const float4*)(xb2),
              xf1 = *(const float4*)(xb2 + 4))
        PHASE(3,
              (c = __shfl(c, (l + 48) & 63), xf2 = *(const float4*)(xb2 + 32)),
              xf3 = *(const float4*)(xb2 + 36),
              (void)0,
              (void)0)
#undef PHASE
#undef STEP

        xw0 = nxw0; xw1 = nxw1; xw2 = nxw2; xw3 = nxw3;
    }
}

extern "C" void kernel_launch(void* const* d_in, const int* in_sizes, int n_in,
                              void* d_out, int out_size, void* d_ws, size_t ws_size,
                              hipStream_t stream) {
    const float* data = (const float*)d_in[0];
    const float* W_ih = (const float*)d_in[1];
    const float* W_hh = (const float*)d_in[2];
    const float* b_ih = (const float*)d_in[3];
    const float* b_hh = (const float*)d_in[4];
    float* out = (float*)d_out;

    hipLaunchKernelGGL(lstm_mfma7, dim3(256), dim3(512), 0, stream,
                       data, W_ih, W_hh, b_ih, b_hh, out);
}